// Round 6
// baseline (1182.858 us; speedup 1.0000x reference)
//
#include <hip/hip_runtime.h>
#include <math.h>

#define T_TOK 1024
#define E_EXP 8
#define H_DIM 2880
#define I_DIM 2880
#define NGU   5760      // 2*I
#define KB    90        // 2880/32
#define TM 128
#define TN 128
#define MAXROWS 3072

typedef __attribute__((ext_vector_type(8))) short short8;
typedef __attribute__((ext_vector_type(8))) int i32x8;
typedef __attribute__((ext_vector_type(4))) float f32x4;
typedef __attribute__((ext_vector_type(16))) float f32x16;

#define PERM(a, b, s) __builtin_amdgcn_perm((uint)(a), (uint)(b), (uint)(s))

// ---- workspace layout (bytes). Total = 129,371,264 == round-3 proven footprint ----
#define FLAGS_OFF 0ull           // int[4]
#define EB_OFF    16ull          // int[8]
#define EPC_OFF   48ull          // int[8]
#define RTOK_OFF  128ull         // MAXROWS int = 12288
#define RW_OFF    12416ull       // MAXROWS float = 12288
#define CGU_OFF   24704ull       // compact gate_up blocks 66,355,200
#define CDB_OFF   66379904ull    // compact down blocks 33,177,600
#define WGS_OFF   99557504ull    // gate_up scales [kb][46080] = 4,147,200
#define WDS_OFF   103704704ull   // down scales [kb][23040] = 2,073,600
#define PATH_OFF  105778304ull
// bf16 path (flags<0):
#define XQ_OFF    (PATH_OFF)                 // 1024*2880 bf16 = 5,898,240
#define ACT_OFF   (PATH_OFF + 5898240ull)    // 3072*2880 bf16 = 17,694,720
// scaled path (flags>=0):
#define XQ8_OFF   (PATH_OFF)                 // 1024*2880 fp8 = 2,949,120
#define XS8_OFF   (PATH_OFF + 2949120ull)    // [kb][tok] 90*1024
#define ACT8_OFF  (PATH_OFF + 3041280ull)    // 3072*2880 fp8
#define AS8_OFF   (PATH_OFF + 11888640ull)   // [cb][row] 90*3072

__device__ inline ushort f2bf(float f) {
  unsigned u = __float_as_uint(f);
  unsigned r = u + 0x7FFFu + ((u >> 16) & 1u);
  return (ushort)(r >> 16);
}

// e = clip(ceil(log2(max(amax,1e-12))), -127, 128)
__device__ inline int blk_exp(float amax) {
  amax = fmaxf(amax, 1e-12f);
  unsigned b = __float_as_uint(amax);
  int e = (int)(b >> 23) - 127;
  if (b & 0x7FFFFFu) e += 1;
  return min(max(e, -127), 128);
}

// quantize v*2^-eblk to fp8 e4m3 (RNE, subnormal lsb 2^-9), dequantize back. [verified r1-r3]
__device__ inline float qdq_val(float v, int eblk) {
  float av = fabsf(v);
  if (av == 0.f) return 0.f;
  int fl = (int)(__float_as_uint(av) >> 23) - 127 - eblk;
  int p = max(fl, -6) - 3;
  float step = ldexpf(1.f, p + eblk);
  return rintf(v / step) * step;
}

// encode x (EXACTLY on the e4m3 grid, |x|<=448) to its e4m3fn byte. No rounding inside.
__device__ inline uint fp8_byte_exact(float x) {
  uint u = __float_as_uint(x);
  uint s = (u >> 24) & 0x80u;
  float ax = fabsf(x);
  if (ax == 0.f) return s;
  int E = (int)((u >> 23) & 0xFFu) - 127;
  uint M = (u >> 20) & 7u;
  if (E >= -6) return s | (uint)((E + 7) << 3) | M;
  return s | (uint)(int)(ax * 512.f + 0.5f);   // subnormal, exact multiple of 2^-9
}

__device__ inline float fp4v(int n) {
  int mag = n & 7;
  float v;
  if (mag == 0) v = 0.f;
  else if (mag == 1) v = 0.5f;
  else v = ldexpf(1.0f + 0.5f * (float)(mag & 1), (mag >> 1) - 1);
  return (n & 8) ? -v : v;
}

__device__ inline uint nibswap(uint w) {
  return ((w & 0x0F0F0F0Fu) << 4) | ((w >> 4) & 0x0F0F0F0Fu);
}

// ---- bf16-path decode helpers [verified r3] ----
struct BTbl { uint tlo_l, tlo_h, thi_l, thi_h; };

__device__ inline BTbl build_tbl(float sc) {
  uint g0 = 0u;
  uint g1 = __float_as_uint(0.5f * sc);
  uint g2 = __float_as_uint(sc);
  uint g3 = __float_as_uint(1.5f * sc);
  uint g4 = __float_as_uint(2.0f * sc);
  uint g5 = __float_as_uint(3.0f * sc);
  uint g6 = __float_as_uint(4.0f * sc);
  uint g7 = __float_as_uint(6.0f * sc);
  uint p01 = PERM(g1, g0, 0x07030602u);
  uint p23 = PERM(g3, g2, 0x07030602u);
  uint p45 = PERM(g5, g4, 0x07030602u);
  uint p67 = PERM(g7, g6, 0x07030602u);
  BTbl t;
  t.tlo_l = PERM(p23, p01, 0x05040100u);
  t.thi_l = PERM(p23, p01, 0x07060302u);
  t.tlo_h = PERM(p67, p45, 0x05040100u);
  t.thi_h = PERM(p67, p45, 0x07060302u);
  return t;
}

// 4 weight bytes (8 fp4, low-nibble-first) -> 8 bf16 in permuted-k order [k0,k2,k4,k6,k1,k3,k5,k7]
__device__ inline uint4 dec_w(uint w, const BTbl& t) {
  uint ml = w & 0x07070707u;
  uint mh = (w >> 4) & 0x07070707u;
  uint sl = (w << 4) & 0x80808080u;
  uint sh = w & 0x80808080u;
  uint hl = PERM(t.thi_h, t.thi_l, ml) | sl;
  uint hh = PERM(t.thi_h, t.thi_l, mh) | sh;
  uint ll = PERM(t.tlo_h, t.tlo_l, ml);
  uint lh = PERM(t.tlo_h, t.tlo_l, mh);
  uint4 o;
  o.x = PERM(hl, ll, 0x05010400u);
  o.y = PERM(hl, ll, 0x07030602u);
  o.z = PERM(hh, lh, 0x05010400u);
  o.w = PERM(hh, lh, 0x07030602u);
  return o;
}

// same k-permutation applied to 8 natural-order bf16
__device__ inline uint4 aperm(uint4 u) {
  uint4 v;
  v.x = PERM(u.y, u.x, 0x05040100u);
  v.y = PERM(u.w, u.z, 0x05040100u);
  v.z = PERM(u.y, u.x, 0x07060302u);
  v.w = PERM(u.w, u.z, 0x07060302u);
  return v;
}

// ================= probe: determine scaled-MFMA conventions on device =================
// Tests (F1: fp4 nibble order) x (F2: scale<->k-half lane mapping) against an exact
// in-kernel reference using the HW-verified C/D layout. flags[0] = winning combo or -1.
__global__ void probe_kernel(int* __restrict__ flags) {
  const int l = threadIdx.x;        // 64 lanes
  const int l31 = l & 31, h = l >> 5;
  const uint E4[7] = {0x00u, 0x38u, 0x40u, 0x44u, 0x48u, 0x4Au, 0x4Cu};

  // A fp8: A[m=l31][k=h*32+j] = ((m+3k)%13)-6, exact in e4m3
  i32x8 af;
#pragma unroll
  for (int r8 = 0; r8 < 8; r8++) {
    uint w = 0;
#pragma unroll
    for (int b = 0; b < 4; b++) {
      int k = h * 32 + r8 * 4 + b;
      int v = ((l31 + 3 * k) % 13) - 6;
      uint byte = E4[v < 0 ? -v : v] | (v < 0 ? 0x80u : 0u);
      w |= byte << (8 * b);
    }
    af[r8] = (int)w;
  }
  // B fp4: code(k, n=l31) = (5k+3n)&15; b0 = low-nibble-first, b1 = high-first
  i32x8 b0v, b1v;
#pragma unroll
  for (int i = 0; i < 8; i++) { b0v[i] = 0; b1v[i] = 0; }
#pragma unroll
  for (int r4 = 0; r4 < 4; r4++) {
    uint w0 = 0, w1 = 0;
#pragma unroll
    for (int i = 0; i < 4; i++) {
      int k0 = h * 32 + r4 * 8 + 2 * i;
      uint c0 = (uint)((k0 * 5 + l31 * 3) & 15);
      uint c1 = (uint)(((k0 + 1) * 5 + l31 * 3) & 15);
      w0 |= (c0 | (c1 << 4)) << (8 * i);
      w1 |= (c1 | (c0 << 4)) << (8 * i);
    }
    b0v[r4] = (int)w0;
    b1v[r4] = (int)w1;
  }

  f32x16 z;
#pragma unroll
  for (int i = 0; i < 16; i++) z[i] = 0.f;

  int best = -1, mask = 0;
  for (int c = 0; c < 4; c++) {
    int f1 = c & 1, f2 = (c >> 1) & 1;
    i32x8 bb = f1 ? b1v : b0v;
    int kidx = h ^ f2;
    int sa = 127 + ((l31 + kidx) & 3);
    int sb = 127 - ((l31 + kidx) & 1);
    f32x16 d = __builtin_amdgcn_mfma_scale_f32_32x32x64_f8f6f4(af, bb, z, 0, 4, 0, sa, 0, sb);
    bool ok = true;
#pragma unroll
    for (int r = 0; r < 16; r++) {
      int row = (r & 3) + 8 * (r >> 2) + 4 * h;
      float ref = 0.f;
      for (int k = 0; k < 64; k++) {
        float fa = (float)(((row + 3 * k) % 13) - 6) * exp2f((float)((row + (k >> 5)) & 3));
        float fb = fp4v((k * 5 + l31 * 3) & 15) * exp2f(-(float)((l31 + (k >> 5)) & 1));
        ref += fa * fb;
      }
      if (fabsf(d[r] - ref) > 0.25f) ok = false;
    }
    if (__all((int)ok)) {
      mask |= (1 << c);
      if (best < 0) best = c;
    }
  }
  if (l == 0) { flags[0] = best; flags[1] = mask; }
}

// ---------------- quant (bf16 path): mxfp8 qdq -> bf16 [verified r1-r3] ----------------
__global__ void quant_x_kernel(const int* __restrict__ flags,
                               const float* __restrict__ x, ushort* __restrict__ xq) {
  if (flags[0] >= 0) return;
  int g = blockIdx.x * 256 + threadIdx.x;   // grid 2880
  float4 v4 = ((const float4*)x)[g];
  float am = fmaxf(fmaxf(fabsf(v4.x), fabsf(v4.y)), fmaxf(fabsf(v4.z), fabsf(v4.w)));
  am = fmaxf(am, __shfl_xor(am, 1));
  am = fmaxf(am, __shfl_xor(am, 2));
  am = fmaxf(am, __shfl_xor(am, 4));
  int eb = blk_exp(am);
  ushort4 o;
  o.x = f2bf(qdq_val(v4.x, eb));
  o.y = f2bf(qdq_val(v4.y, eb));
  o.z = f2bf(qdq_val(v4.z, eb));
  o.w = f2bf(qdq_val(v4.w, eb));
  ((ushort4*)xq)[g] = o;
}

// ---------------- quant (scaled path): mxfp8 -> fp8 bytes + E8M0 scales ----------------
__global__ void quant_x8_kernel(const int* __restrict__ flags,
                                const float* __restrict__ x, uint* __restrict__ xq8,
                                uchar* __restrict__ xs8) {
  if (flags[0] < 0) return;
  int g = blockIdx.x * 256 + threadIdx.x;   // grid 2880
  float4 v = ((const float4*)x)[g];
  float am = fmaxf(fmaxf(fabsf(v.x), fabsf(v.y)), fmaxf(fabsf(v.z), fabsf(v.w)));
  am = fmaxf(am, __shfl_xor(am, 1));
  am = fmaxf(am, __shfl_xor(am, 2));
  am = fmaxf(am, __shfl_xor(am, 4));
  int eb = blk_exp(am);
  float s = ldexpf(1.f, -eb);
  uint b0 = fp8_byte_exact(qdq_val(v.x * s, 0));
  uint b1 = fp8_byte_exact(qdq_val(v.y * s, 0));
  uint b2 = fp8_byte_exact(qdq_val(v.z * s, 0));
  uint b3 = fp8_byte_exact(qdq_val(v.w * s, 0));
  xq8[g] = b0 | (b1 << 8) | (b2 << 16) | (b3 << 24);
  if ((g & 7) == 0) {
    int tok = g / 720;
    int kb = (g - tok * 720) >> 3;
    xs8[kb * T_TOK + tok] = (uchar)(eb + 127);
  }
}

// ---------------- routing ----------------
__global__ void routing_kernel(const int* __restrict__ eidx, const float* __restrict__ rwt,
                               int* __restrict__ rtok, float* __restrict__ rw,
                               int* __restrict__ ebase, int* __restrict__ epc) {
  __shared__ int cnt[E_EXP];
  __shared__ int base_s[E_EXP];
  __shared__ int pos[E_EXP];
  int t = threadIdx.x;
  if (t < E_EXP) cnt[t] = 0;
  __syncthreads();
  for (int p = t; p < T_TOK * 2; p += 256) atomicAdd(&cnt[eidx[p]], 1);
  __syncthreads();
  if (t == 0) {
    int b = 0;
    for (int e = 0; e < E_EXP; e++) {
      base_s[e] = b;
      b += ((cnt[e] + TM - 1) / TM) * TM;
    }
  }
  __syncthreads();
  if (t < E_EXP) {
    pos[t] = 0;
    ebase[t] = base_s[t];
    epc[t] = ((cnt[t] + TM - 1) / TM) * TM;
  }
  __syncthreads();
  for (int p = t; p < T_TOK * 2; p += 256) {
    int e = eidx[p];
    int o = atomicAdd(&pos[e], 1);
    rtok[base_s[e] + o] = p >> 1;
    rw[base_s[e] + o] = rwt[p];
  }
  __syncthreads();
  for (int e = 0; e < E_EXP; e++) {
    int c = cnt[e], pc = ((c + TM - 1) / TM) * TM;
    for (int i = c + t; i < pc; i += 256) {
      rtok[base_s[e] + i] = 0;
      rw[base_s[e] + i] = 0.f;
    }
  }
}

// ---------------- repack blocks: int32-per-byte -> packed bytes (+F1 nibble swap) ----------------
__global__ void repack_kernel(const int* __restrict__ flags,
                              const int* __restrict__ src, uint4* __restrict__ dst, int n16) {
  int g = blockIdx.x * 256 + threadIdx.x;
  if (g >= n16) return;
  uint f1 = (flags[0] >= 0 && (flags[0] & 1)) ? 1u : 0u;
  const int4* s = (const int4*)(src) + g * 4;
  int4 w0 = s[0], w1 = s[1], w2 = s[2], w3 = s[3];
  uint4 o;
  o.x = (uint)(w0.x & 255) | ((uint)(w0.y & 255) << 8) | ((uint)(w0.z & 255) << 16) | ((uint)(w0.w) << 24);
  o.y = (uint)(w1.x & 255) | ((uint)(w1.y & 255) << 8) | ((uint)(w1.z & 255) << 16) | ((uint)(w1.w) << 24);
  o.z = (uint)(w2.x & 255) | ((uint)(w2.y & 255) << 8) | ((uint)(w2.z & 255) << 16) | ((uint)(w2.w) << 24);
  o.w = (uint)(w3.x & 255) | ((uint)(w3.y & 255) << 8) | ((uint)(w3.z & 255) << 16) | ((uint)(w3.w) << 24);
  if (f1) { o.x = nibswap(o.x); o.y = nibswap(o.y); o.z = nibswap(o.z); o.w = nibswap(o.w); }
  dst[g] = o;
}

// ---------------- repack scales transposed: src [R][90] int32 -> dst [90][R] bytes ----------------
__global__ void repack_scale_kernel(const int* __restrict__ src, uchar* __restrict__ dst, int R) {
  int r = blockIdx.x * 256 + threadIdx.x;
  int kb = blockIdx.y;
  dst[(size_t)kb * R + r] = (uchar)src[(size_t)r * KB + kb];
}

// ================= scaled path (flags >= 0) =================
__global__ __launch_bounds__(256, 3)
void gemm1s_kernel(const int* __restrict__ flags,
                   const uchar* __restrict__ xq8, const uchar* __restrict__ xs8,
                   const uchar* __restrict__ cgu, const uchar* __restrict__ wgs,
                   const float* __restrict__ gubias,
                   const int* __restrict__ rtok, const int* __restrict__ ebase,
                   const int* __restrict__ epc,
                   uchar* __restrict__ act8, uchar* __restrict__ as8) {
  const int fl = flags[0];
  if (fl < 0) return;
  const int f2 = (fl >> 1) & 1;
  const int ntile = blockIdx.x;
  const int e = blockIdx.y >> 4;
  const int mtile = blockIdx.y & 15;
  if (mtile * TM >= epc[e]) return;
  const int rowbase = ebase[e] + mtile * TM;

  __shared__ __align__(16) uchar lA[128 * 80];
  __shared__ __align__(16) uchar lB[128 * 48];
  __shared__ uchar sAs[KB * 128];
  __shared__ uchar sBs[KB * 128];
  __shared__ int ltok[128];

  const int tid = threadIdx.x;
  const int wave = tid >> 6, lane = tid & 63;
  const int half = tid & 1, srow = tid >> 1;
  const int wm = (wave & 1) * 64, wn = (wave >> 1) * 64;
  const int l31 = lane & 31, l5 = lane >> 5;

  if (tid < 128) ltok[tid] = rtok[rowbase + tid];
  __syncthreads();
  for (int i = tid; i < KB * 128; i += 256) {
    int kb = i >> 7, r = i & 127;
    sAs[i] = xs8[kb * T_TOK + ltok[r]];
    sBs[i] = wgs[(size_t)kb * 46080 + e * NGU + ntile * 128 + r];
  }

  const int tokA = ltok[srow];
  const uchar* aSrc = xq8 + (size_t)tokA * H_DIM + half * 32;
  const int nrow = ntile * TN + srow;
  const uchar* bSrc = cgu + (size_t)(e * NGU + nrow) * 1440 + half * 16;

  f32x16 acc[2][2];
#pragma unroll
  for (int i = 0; i < 2; i++)
#pragma unroll
    for (int j = 0; j < 2; j++)
#pragma unroll
      for (int r = 0; r < 16; r++) acc[i][j][r] = 0.f;

  uint4 pa0 = *(const uint4*)(aSrc);
  uint4 pa1 = *(const uint4*)(aSrc + 16);
  uint4 pb = *(const uint4*)(bSrc);

  for (int kb2 = 0; kb2 < 45; kb2++) {
    const int nk = (kb2 + 1 < 45) ? kb2 + 1 : kb2;
    uint4 na0 = *(const uint4*)(aSrc + nk * 64);
    uint4 na1 = *(const uint4*)(aSrc + nk * 64 + 16);
    uint4 nb = *(const uint4*)(bSrc + nk * 32);

    __syncthreads();
    *(uint4*)&lA[srow * 80 + half * 32] = pa0;
    *(uint4*)&lA[srow * 80 + half * 32 + 16] = pa1;
    *(uint4*)&lB[srow * 48 + half * 16] = pb;
    __syncthreads();

    i32x8 af[2], bf2[2];
    int sa[2], sb[2];
#pragma unroll
    for (int f = 0; f < 2; f++) {
      const uchar* pr = &lA[(wm + f * 32 + l31) * 80 + l5 * 32];
      uint4 lo = *(const uint4*)pr;
      uint4 hi = *(const uint4*)(pr + 16);
      af[f][0] = lo.x; af[f][1] = lo.y; af[f][2] = lo.z; af[f][3] = lo.w;
      af[f][4] = hi.x; af[f][5] = hi.y; af[f][6] = hi.z; af[f][7] = hi.w;
      uint4 bb = *(const uint4*)&lB[(wn + f * 32 + l31) * 48 + l5 * 16];
      bf2[f][0] = bb.x; bf2[f][1] = bb.y; bf2[f][2] = bb.z; bf2[f][3] = bb.w;
      bf2[f][4] = 0; bf2[f][5] = 0; bf2[f][6] = 0; bf2[f][7] = 0;
      int kidx = kb2 * 2 + (l5 ^ f2);
      sa[f] = sAs[kidx * 128 + wm + f * 32 + l31];
      sb[f] = sBs[kidx * 128 + wn + f * 32 + l31];
    }
#pragma unroll
    for (int fm = 0; fm < 2; fm++)
#pragma unroll
      for (int fn = 0; fn < 2; fn++)
        acc[fm][fn] = __builtin_amdgcn_mfma_scale_f32_32x32x64_f8f6f4(
            af[fm], bf2[fn], acc[fm][fn], 0, 4, 0, sa[fm], 0, sb[fn]);

    pa0 = na0; pa1 = na1; pb = nb;
  }

  const int nb0 = ntile * 128 + wn;
  const float bias0 = gubias[e * NGU + nb0 + l31];
  const float bias1 = gubias[e * NGU + nb0 + 32 + l31];
  const bool evenl = (lane & 1) == 0;
  const int cb_ix = ntile * 2 + (wn >> 6);
  const int cbase = ntile * 64 + (wn >> 1) + (l31 >> 1);
#pragma unroll
  for (int fm = 0; fm < 2; fm++) {
#pragma unroll
    for (int r = 0; r < 16; r++) {
      int row = rowbase + wm + fm * 32 + (r & 3) + 8 * (r >> 2) + l5 * 4;
      float h0 = acc[fm][0][r] + bias0;
      float h1 = acc[fm][1][r] + bias1;
      float p0 = __shfl_xor(h0, 1);
      float p1 = __shfl_xor(h1, 1);
      float g0 = evenl ? h0 : p0, u0 = evenl ? p0 : h0;
      float g1 = evenl ? h1 : p1, u1 = evenl ? p1 : h1;
      g0 = fminf(g0, 7.f); u0 = fminf(fmaxf(u0, -7.f), 7.f);
      g1 = fminf(g1, 7.f); u1 = fminf(fmaxf(u1, -7.f), 7.f);
      float a0 = (u0 + 1.f) * (g0 / (1.f + expf(-1.702f * g0)));
      float a1 = (u1 + 1.f) * (g1 / (1.f + expf(-1.702f * g1)));
      float am = fmaxf(fabsf(a0), fabsf(a1));
      am = fmaxf(am, __shfl_xor(am, 2));
      am = fmaxf(am, __shfl_xor(am, 4));
      am = fmaxf(am, __shfl_xor(am, 8));
      am = fmaxf(am, __shfl_xor(am, 16));
      int eb = blk_exp(am);
      if (l31 == 0) as8[(size_t)cb_ix * MAXROWS + row] = (uchar)(eb + 127);
      if (evenl) {
        float s = ldexpf(1.f, -eb);
        act8[(size_t)row * I_DIM + cbase] = (uchar)fp8_byte_exact(qdq_val(a0 * s, 0));
        act8[(size_t)row * I_DIM + cbase + 16] = (uchar)fp8_byte_exact(qdq_val(a1 * s, 0));
      }
    }
  }
}

__global__ __launch_bounds__(256, 3)
void gemm2s_kernel(const int* __restrict__ flags,
                   const uchar* __restrict__ act8, const uchar* __restrict__ as8,
                   const uchar* __restrict__ cdb, const uchar* __restrict__ wds,
                   const float* __restrict__ dbias,
                   const int* __restrict__ rtok, const float* __restrict__ rw,
                   const int* __restrict__ ebase, const int* __restrict__ epc,
                   float* __restrict__ out) {
  const int fl = flags[0];
  if (fl < 0) return;
  const int f2 = (fl >> 1) & 1;
  const int ntile = blockIdx.x;
  const int e = blockIdx.y >> 4;
  const int mtile = blockIdx.y & 15;
  if (mtile * TM >= epc[e]) return;
  const int rowbase = ebase[e] + mtile * TM;
  const int kz = blockIdx.z;
  const int klo = kz * 23;
  const int khi = kz ? 45 : 23;

  __shared__ __align__(16) uchar lA[128 * 80];
  __shared__ __align__(16) uchar lB[128 * 48];
  __shared__ uchar sAs[KB * 128];
  __shared__ uchar sBs[KB * 128];

  const int tid = threadIdx.x;
  const int wave = tid >> 6, lane = tid & 63;
  const int half = tid & 1, srow = tid >> 1;
  const int wm = (wave & 1) * 64, wn = (wave >> 1) * 64;
  const int l31 = lane & 31, l5 = lane >> 5;

  for (int i = tid; i < KB * 128; i += 256) {
    int kb = i >> 7, r = i & 127;
    int rr = min(ntile * 128 + r, H_DIM - 1);
    sAs[i] = as8[(size_t)kb * MAXROWS + rowbase + r];
    sBs[i] = wds[(size_t)kb * 23040 + e * H_DIM + rr];
  }

  const uchar* aSrc = act8 + (size_t)(rowbase + srow) * I_DIM + half * 32;
  const int nrow = min(ntile * TN + srow, H_DIM - 1);
  const uchar* bSrc = cdb + (size_t)(e * H_DIM + nrow) * 1440 + half * 16;

  f32x16 acc[2][2];
#pragma unroll
  for (int i = 0; i < 2; i++)
#pragma unroll
    for (int j = 0; j < 2; j++)
#pragma unroll
      for (int r = 0; r < 16; r++) acc[i][j][r] = 0.f;

  uint4 pa0 = *(const uint4*)(aSrc + klo * 64);
  uint4 pa1 = *(const uint4*)(aSrc + klo * 64 + 16);
  uint4 pb = *(const uint4*)(bSrc + klo * 32);

  for (int kb2 = klo; kb2 < khi; kb2++) {
    const int nk = (kb2 + 1 < khi) ? kb2 + 1 : kb2;
    uint4 na0 = *(const uint4*)(aSrc + nk * 64);
    uint4 na1 = *(const uint4*)(aSrc + nk * 64 + 16);
    uint4 nb = *(const uint4*)(bSrc + nk * 32);

    __syncthreads();
    *(uint4*)&lA[srow * 80 + half * 32] = pa0;
    *(uint4*)&lA[srow * 80 + half * 32 + 16] = pa1;
    *(uint4*)&lB[srow * 48 + half * 16] = pb;
    __syncthreads();

    i32x8 af[2], bf2[2];
    int sa[2], sb[2];
#pragma unroll
    for (int f = 0; f < 2; f++) {
      const uchar* pr = &lA[(wm + f * 32 + l31) * 80 + l5 * 32];
      uint4 lo = *(const uint4*)pr;
      uint4 hi = *(const uint4*)(pr + 16);
      af[f][0] = lo.x; af[f][1] = lo.y; af[f][2] = lo.z; af[f][3] = lo.w;
      af[f][4] = hi.x; af[f][5] = hi.y; af[f][6] = hi.z; af[f][7] = hi.w;
      uint4 bb = *(const uint4*)&lB[(wn + f * 32 + l31) * 48 + l5 * 16];
      bf2[f][0] = bb.x; bf2[f][1] = bb.y; bf2[f][2] = bb.z; bf2[f][3] = bb.w;
      bf2[f][4] = 0; bf2[f][5] = 0; bf2[f][6] = 0; bf2[f][7] = 0;
      int kidx = kb2 * 2 + (l5 ^ f2);
      sa[f] = sAs[kidx * 128 + wm + f * 32 + l31];
      sb[f] = sBs[kidx * 128 + wn + f * 32 + l31];
    }
#pragma unroll
    for (int fm = 0; fm < 2; fm++)
#pragma unroll
      for (int fn = 0; fn < 2; fn++)
        acc[fm][fn] = __builtin_amdgcn_mfma_scale_f32_32x32x64_f8f6f4(
            af[fm], bf2[fn], acc[fm][fn], 0, 4, 0, sa[fm], 0, sb[fn]);

    pa0 = na0; pa1 = na1; pb = nb;
  }

  const int nb0 = ntile * 128 + wn;
  float bias0 = 0.f, bias1 = 0.f;
  if (kz == 0) {
    bias0 = (nb0 + l31 < H_DIM) ? dbias[e * H_DIM + nb0 + l31] : 0.f;
    bias1 = (nb0 + 32 + l31 < H_DIM) ? dbias[e * H_DIM + nb0 + 32 + l31] : 0.f;
  }
#pragma unroll
  for (int fm = 0; fm < 2; fm++) {
#pragma unroll
    for (int r = 0; r < 16; r++) {
      int orow = rowbase + wm + fm * 32 + (r & 3) + 8 * (r >> 2) + l5 * 4;
      int tok = rtok[orow];
      float w = rw[orow];
      if (w != 0.f) {
        int n0 = nb0 + l31;
        int n1 = nb0 + 32 + l31;
        if (n0 < H_DIM) atomicAdd(&out[(size_t)tok * H_DIM + n0], w * (acc[fm][0][r] + bias0));
        if (n1 < H_DIM) atomicAdd(&out[(size_t)tok * H_DIM + n1], w * (acc[fm][1][r] + bias1));
      }
    }
  }
}

// ================= bf16 fallback path (flags < 0) [verified r3; scales from wgs/wds] =================
__global__ __launch_bounds__(256, 2)
void gemm1c_kernel(const int* __restrict__ flags,
                   const ushort* __restrict__ xq,
                   const uchar* __restrict__ cgu, const uchar* __restrict__ wgs,
                   const float* __restrict__ gubias,
                   const int* __restrict__ rtok, const int* __restrict__ ebase,
                   const int* __restrict__ epc,
                   ushort* __restrict__ act) {
  if (flags[0] >= 0) return;
  const int ntile = blockIdx.x;
  const int e = blockIdx.y >> 4;
  const int mtile = blockIdx.y & 15;
  if (mtile * TM >= epc[e]) return;
  const int rowbase = ebase[e] + mtile * TM;

  __shared__ __align__(16) ushort lA[TM][40];
  __shared__ __align__(16) ushort lB[TN][40];

  const int tid = threadIdx.x;
  const int wave = tid >> 6, lane = tid & 63;
  const int half = tid & 1, srow = tid >> 1;
  const int wm = (wave & 1) * 64, wn = (wave >> 1) * 64;
  const int lrow = lane & 15, q = lane >> 4;

  const int tokA = rtok[rowbase + srow];
  const ushort* aSrc = xq + tokA * H_DIM + half * 16;
  const int nrow = ntile * TN + srow;
  const uchar* bSrc = cgu + (size_t)(e * NGU + nrow) * 1440 + half * 8;
  const uchar* sSrc = wgs + (size_t)(e * NGU + nrow);

  f32x4 acc[4][4];
#pragma unroll
  for (int i = 0; i < 4; i++)
#pragma unroll
    for (int j = 0; j < 4; j++) acc[i][j] = (f32x4){0.f, 0.f, 0.f, 0.f};

  uint4 a0 = ((const uint4*)(aSrc))[0];
  uint4 a1 = ((const uint4*)(aSrc))[1];
  uint2 bw = *(const uint2*)(bSrc);
  uchar sb = sSrc[0];

  for (int kb = 0; kb < KB; kb++) {
    const int nk = (kb + 1 < KB) ? kb + 1 : kb;
    uint4 na0 = ((const uint4*)(aSrc + nk * 32))[0];
    uint4 na1 = ((const uint4*)(aSrc + nk * 32))[1];
    uint2 nbw = *(const uint2*)(bSrc + nk * 16);
    uchar nsb = sSrc[(size_t)nk * 46080];

    float sc = ldexpf(1.f, (int)sb - 127);
    BTbl t = build_tbl(sc);
    uint4 d0 = dec_w(bw.x, t);
    uint4 d1 = dec_w(bw.y, t);
    uint4 pa0 = aperm(a0);
    uint4 pa1 = aperm(a1);

    __syncthreads();
    *(uint4*)&lA[srow][half * 16] = pa0;
    *(uint4*)&lA[srow][half * 16 + 8] = pa1;
    *(uint4*)&lB[srow][half * 16] = d0;
    *(uint4*)&lB[srow][half * 16 + 8] = d1;
    __syncthreads();

    short8 af[4], bfr[4];
#pragma unroll
    for (int mi = 0; mi < 4; mi++) af[mi] = *(const short8*)&lA[wm + mi * 16 + lrow][q * 8];
#pragma unroll
    for (int ni = 0; ni < 4; ni++) bfr[ni] = *(const short8*)&lB[wn + ni * 16 + lrow][q * 8];
#pragma unroll
    for (int mi = 0; mi < 4; mi++)
#pragma unroll
      for (int ni = 0; ni < 4; ni++)
        acc[mi][ni] = __builtin_amdgcn_mfma_f32_16x16x32_bf16(af[mi], bfr[ni], acc[mi][ni], 0, 0, 0);

    a0 = na0; a1 = na1; bw = nbw; sb = nsb;
  }

  const int nbase = ntile * TN + wn;
  float bias_v[4];
#pragma unroll
  for (int ni = 0; ni < 4; ni++) bias_v[ni] = gubias[e * NGU + nbase + ni * 16 + lrow];
  const bool evenl = (lane & 1) == 0;
#pragma unroll
  for (int mi = 0; mi < 4; mi++) {
    float av[4][4];
#pragma unroll
    for (int ni = 0; ni < 4; ni++)
#pragma unroll
      for (int r = 0; r < 4; r++) {
        float h = acc[mi][ni][r] + bias_v[ni];
        float pp = __shfl_xor(h, 1);
        float gate = evenl ? h : pp;
        float up = evenl ? pp : h;
        gate = fminf(gate, 7.f);
        up = fminf(fmaxf(up, -7.f), 7.f);
        float glu = gate / (1.f + expf(-1.702f * gate));
        av[ni][r] = (up + 1.f) * glu;
      }
#pragma unroll
    for (int r = 0; r < 4; r++) {
      float am = 0.f;
#pragma unroll
      for (int ni = 0; ni < 4; ni++) am = fmaxf(am, fabsf(av[ni][r]));
      am = fmaxf(am, __shfl_xor(am, 2));
      am = fmaxf(am, __shfl_xor(am, 4));
      am = fmaxf(am, __shfl_xor(am, 8));
      int eb = blk_exp(am);
      if (evenl) {
        int row = rowbase + wm + mi * 16 + q * 4 + r;
        int cb = (nbase >> 1) + (lrow >> 1);
#pragma unroll
        for (int ni = 0; ni < 4; ni++)
          act[row * I_DIM + cb + ni * 8] = f2bf(qdq_val(av[ni][r], eb));
      }
    }
  }
}

__global__ __launch_bounds__(256, 2)
void gemm2c_kernel(const int* __restrict__ flags,
                   const ushort* __restrict__ act,
                   const uchar* __restrict__ cdb, const uchar* __restrict__ wds,
                   const float* __restrict__ dbias,
                   const int* __restrict__ rtok, const float* __restrict__ rw,
                   const int* __restrict__ ebase, const int* __restrict__ epc,
                   float* __restrict__ out) {
  if (flags[0] >= 0) return;
  const int ntile = blockIdx.x;
  const int e = blockIdx.y >> 4;
  const int mtile = blockIdx.y & 15;
  if (mtile * TM >= epc[e]) return;
  const int rowbase = ebase[e] + mtile * TM;
  const int kz = blockIdx.z;
  const int kb0 = kz * (KB / 2), kb1 = kb0 + (KB / 2);

  __shared__ __align__(16) ushort lA[TM][40];
  __shared__ __align__(16) ushort lB[TN][40];

  const int tid = threadIdx.x;
  const int wave = tid >> 6, lane = tid & 63;
  const int half = tid & 1, srow = tid >> 1;
  const int wm = (wave & 1) * 64, wn = (wave >> 1) * 64;
  const int lrow = lane & 15, q = lane >> 4;

  const ushort* aSrc = act + (size_t)(rowbase + srow) * I_DIM + half * 16;
  int nrow = ntile * TN + srow;
  if (nrow >= H_DIM) nrow = H_DIM - 1;
  const uchar* bSrc = cdb + (size_t)(e * H_DIM + nrow) * 1440 + half * 8;
  const uchar* sSrc = wds + (size_t)(e * H_DIM + nrow);

  f32x4 acc[4][4];
#pragma unroll
  for (int i = 0; i < 4; i++)
#pragma unroll
    for (int j = 0; j < 4; j++) acc[i][j] = (f32x4){0.f, 0.f, 0.f, 0.f};

  uint4 a0 = ((const uint4*)(aSrc + kb0 * 32))[0];
  uint4 a1 = ((const uint4*)(aSrc + kb0 * 32))[1];
  uint2 bw = *(const uint2*)(bSrc + kb0 * 16);
  uchar sb = sSrc[(size_t)kb0 * 23040];

  for (int kb = kb0; kb < kb1; kb++) {
    const int nk = (kb + 1 < kb1) ? kb + 1 : kb;
    uint4 na0 = ((const uint4*)(aSrc + nk * 32))[0];
    uint4 na1 = ((const uint4*)(aSrc + nk * 32))[1];
    uint2 nbw = *(const uint2*)(bSrc + nk * 16);
    uchar nsb = sSrc[(size_t)nk * 23040];

    float sc = ldexpf(1.f, (int)sb - 127);
    BTbl t = build_tbl(sc);
    uint4 d0 = dec_w(bw.x, t);
    uint4 d1 = dec_w(bw.y, t);
    uint4 pa0 = aperm(a0);
    uint4 pa1 = aperm(a1);

    __syncthreads();
    *(uint4*)&lA[srow][half * 16] = pa0;
    *(uint4*)&lA[srow][half * 16 + 8] = pa1;
    *(uint4*)&lB[srow][half * 16] = d0;
    *(uint4*)&lB[srow][half * 16 + 8] = d1;
    __syncthreads();

    short8 af[4], bfr[4];
#pragma unroll
    for (int mi = 0; mi < 4; mi++) af[mi] = *(const short8*)&lA[wm + mi * 16 + lrow][q * 8];
#pragma unroll
    for (int ni = 0; ni < 4; ni++) bfr[ni] = *(const short8*)&lB[wn + ni * 16 + lrow][q * 8];
#pragma unroll
    for (int mi = 0; mi < 4; mi++)
#pragma unroll
      for (int ni = 0; ni < 4; ni++)
        acc[mi][ni] = __builtin_amdgcn_mfma_f32_16x16x32_bf16(af[mi], bfr[ni], acc[mi][ni], 0, 0, 0);

    a0 = na0; a1 = na1; bw = nbw; sb = nsb;
  }

  const int nbase = ntile * TN + wn;
  float bias_v[4];
#pragma unroll
  for (int ni = 0; ni < 4; ni++) {
    int n = nbase + ni * 16 + lrow;
    bias_v[ni] = (kz == 0 && n < H_DIM) ? dbias[e * H_DIM + n] : 0.f;
  }
#pragma unroll
  for (int mi = 0; mi < 4; mi++)
#pragma unroll
    for (int r = 0; r < 4; r++) {
      int orow = rowbase + wm + mi * 16 + q * 4 + r;
      int tok = rtok[orow];
      float w = rw[orow];
      if (w != 0.f) {
#pragma unroll
        for (int ni = 0; ni < 4; ni++) {
          int n = nbase + ni * 16 + lrow;
          if (n < H_DIM) atomicAdd(&out[tok * H_DIM + n], w * (acc[mi][ni][r] + bias_v[ni]));
        }
      }
    }
}

extern "C" void kernel_launch(void* const* d_in, const int* in_sizes, int n_in,
                              void* d_out, int out_size, void* d_ws, size_t ws_size,
                              hipStream_t stream) {
  const float* hs = (const float*)d_in[0];
  const int* eidx = (const int*)d_in[1];
  const float* rwt = (const float*)d_in[2];
  const int* gub = (const int*)d_in[3];
  const int* gus = (const int*)d_in[4];
  const float* gubias = (const float*)d_in[5];
  const int* db = (const int*)d_in[6];
  const int* dsc = (const int*)d_in[7];
  const float* dbias = (const float*)d_in[8];
  float* out = (float*)d_out;
  char* ws = (char*)d_ws;

  int* flags = (int*)(ws + FLAGS_OFF);
  int* ebase = (int*)(ws + EB_OFF);
  int* epc = (int*)(ws + EPC_OFF);
  int* rtok = (int*)(ws + RTOK_OFF);
  float* rw = (float*)(ws + RW_OFF);
  uchar* cgu = (uchar*)(ws + CGU_OFF);
  uchar* cdb = (uchar*)(ws + CDB_OFF);
  uchar* wgs = (uchar*)(ws + WGS_OFF);
  uchar* wds = (uchar*)(ws + WDS_OFF);
  ushort* xq = (ushort*)(ws + XQ_OFF);
  ushort* act = (ushort*)(ws + ACT_OFF);
  uint* xq8 = (uint*)(ws + XQ8_OFF);
  uchar* xs8 = (uchar*)(ws + XS8_OFF);
  uchar* act8 = (uchar*)(ws + ACT8_OFF);
  uchar* as8 = (uchar*)(ws + AS8_OFF);

  hipMemsetAsync(d_out, 0, (size_t)out_size * sizeof(float), stream);
  probe_kernel<<<1, 64, 0, stream>>>(flags);
  routing_kernel<<<1, 256, 0, stream>>>(eidx, rwt, rtok, rw, ebase, epc);
  quant_x_kernel<<<2880, 256, 0, stream>>>(flags, hs, xq);
  quant_x8_kernel<<<2880, 256, 0, stream>>>(flags, hs, xq8, xs8);
  repack_kernel<<<16200, 256, 0, stream>>>(flags, gub, (uint4*)cgu, 4147200);
  repack_kernel<<<8100, 256, 0, stream>>>(flags, db, (uint4*)cdb, 2073600);
  repack_scale_kernel<<<dim3(180, 90), 256, 0, stream>>>(gus, wgs, 46080);
  repack_scale_kernel<<<dim3(90, 90), 256, 0, stream>>>(dsc, wds, 23040);
  // scaled path (no-op if probe failed)
  gemm1s_kernel<<<dim3(45, 128), 256, 0, stream>>>(flags, (const uchar*)xq8, xs8, cgu, wgs,
                                                   gubias, rtok, ebase, epc, act8, as8);
  gemm2s_kernel<<<dim3(23, 128, 2), 256, 0, stream>>>(flags, act8, as8, cdb, wds, dbias,
                                                      rtok, rw, ebase, epc, out);
  // bf16 fallback path (no-op if probe succeeded)
  gemm1c_kernel<<<dim3(45, 128), 256, 0, stream>>>(flags, xq, cgu, wgs, gubias,
                                                   rtok, ebase, epc, act);
  gemm2c_kernel<<<dim3(23, 128, 2), 256, 0, stream>>>(flags, act, cdb, wds, dbias,
                                                      rtok, rw, ebase, epc, out);
}